// Round 1
// baseline (260.433 us; speedup 1.0000x reference)
//
#include <hip/hip_runtime.h>

// Volume: [B=2, X=128, Y=128, Z=128, C=1], grid: [B=2, N=2^21, 3] in [0,1].
// Output: [B, N, 1] fp32 trilinear samples.
// Layout: image flat index = b*128^3 + x*128^2 + y*128 + z  (z fastest).

#define TOTAL   (2 * 2097152)   // B * N
#define LOG2N   21              // N = 2^21 per batch
#define VOL     (128 * 128 * 128)

__global__ __launch_bounds__(256)
void ImageWarped_trilinear_kernel(const float* __restrict__ image,
                                  const float* __restrict__ grid,
                                  float* __restrict__ out)
{
    const int i = blockIdx.x * 256 + threadIdx.x;
    if (i >= TOTAL) return;

    // grid is [B*N, 3] flat; thread i reads 3 consecutive floats (stride 12B,
    // wave touches 768B contiguous -> fully coalesced at line granularity).
    const float gx = grid[3 * i + 0];
    const float gy = grid[3 * i + 1];
    const float gz = grid[3 * i + 2];

    const int b = i >> LOG2N;
    const float* __restrict__ img = image + (size_t)b * VOL;

    // idx = clip(grid * 128, 0.001, 126.999)  -- min(SIZE)-1.001 for all dims
    const float xf = fminf(fmaxf(gx * 128.0f, 0.001f), 126.999f);
    const float yf = fminf(fmaxf(gy * 128.0f, 0.001f), 126.999f);
    const float zf = fminf(fmaxf(gz * 128.0f, 0.001f), 126.999f);

    const float x1f = floorf(xf), x2f = ceilf(xf);
    const float y1f = floorf(yf), y2f = ceilf(yf);
    const float z1f = floorf(zf), z2f = ceilf(zf);

    // Weights exactly as the reference (NOT 1-w: if coord is integral,
    // floor==ceil and both weights are 0 -> output 0 contribution).
    const float wx  = xf - x1f, wx2 = x2f - xf;
    const float wy  = yf - y1f, wy2 = y2f - yf;
    const float wz  = zf - z1f, wz2 = z2f - zf;

    const int ix1 = (int)x1f, ix2 = (int)x2f;
    const int iy1 = (int)y1f, iy2 = (int)y2f;
    const int iz1 = (int)z1f, iz2 = (int)z2f;

    // Corner offsets: x stride 16384, y stride 128, z stride 1.
    const int bx1 = ix1 << 14, bx2 = ix2 << 14;
    const int by1 = iy1 << 7,  by2 = iy2 << 7;

    const float c111 = img[bx1 + by1 + iz1];  // (x1,y1,z1)
    const float c211 = img[bx2 + by1 + iz1];  // (x2,y1,z1)
    const float c121 = img[bx1 + by2 + iz1];  // (x1,y2,z1)
    const float c221 = img[bx2 + by2 + iz1];  // (x2,y2,z1)
    const float c112 = img[bx1 + by1 + iz2];  // (x1,y1,z2)
    const float c212 = img[bx2 + by1 + iz2];  // (x2,y1,z2)
    const float c122 = img[bx1 + by2 + iz2];  // (x1,y2,z2)
    const float c222 = img[bx2 + by2 + iz2];  // (x2,y2,z2)

    // lerp_y1 = (g(x2,y1,z1)*wx + g(x1,y1,z1)*wx2)*wy2 + (g(x2,y2,z1)*wx + g(x1,y2,z1)*wx2)*wy
    const float lerp_y1 = (c211 * wx + c111 * wx2) * wy2
                        + (c221 * wx + c121 * wx2) * wy;
    const float lerp_y2 = (c212 * wx + c112 * wx2) * wy2
                        + (c222 * wx + c122 * wx2) * wy;

    out[i] = lerp_y2 * wz + lerp_y1 * wz2;
}

extern "C" void kernel_launch(void* const* d_in, const int* in_sizes, int n_in,
                              void* d_out, int out_size, void* d_ws, size_t ws_size,
                              hipStream_t stream)
{
    const float* image = (const float*)d_in[0];  // [2,128,128,128,1] fp32
    const float* grid  = (const float*)d_in[1];  // [2,2097152,3]     fp32
    float* out = (float*)d_out;                  // [2,2097152,1]     fp32

    const int blocks = (TOTAL + 255) / 256;      // 16384
    ImageWarped_trilinear_kernel<<<blocks, 256, 0, stream>>>(image, grid, out);
}

// Round 2
// 215.648 us; speedup vs baseline: 1.2077x; 1.2077x over previous
//
#include <hip/hip_runtime.h>
#include <hip/hip_fp16.h>

// Volume: [B=2, X=128, Y=128, Z=128, C=1] fp32, grid: [B=2, N=2^21, 3] in [0,1].
// Output: [B, N, 1] fp32 trilinear samples.
// image flat index = b*128^3 + x*128^2 + y*128 + z  (z fastest).
//
// Strategy (R2): convert image fp32 -> fp16 in d_ws. Per-batch volume shrinks
// 8.4 MiB -> 4.19 MiB, which fits in each XCD's 4 MiB L2 -> random corner
// gathers become L2 hits instead of 64B HBM line misses (R1: 594 MB FETCH).

#define TOTAL   (2 * 2097152)   // B * N samples
#define LOG2N   21              // N = 2^21 per batch
#define VOL     (128 * 128 * 128)
#define NVOX    (2 * VOL)       // total voxels = 4,194,304

// ---- pre-pass: fp32 volume -> fp16 volume in workspace -------------------
__global__ __launch_bounds__(256)
void ImageWarped_cvt_fp16_kernel(const float* __restrict__ in,
                                 __half* __restrict__ out)
{
    const int i = blockIdx.x * 256 + threadIdx.x;   // NVOX/4 threads
    const float4 v = ((const float4*)in)[i];
    union { __half2 h2[2]; uint2 u; } p;
    p.h2[0] = __floats2half2_rn(v.x, v.y);
    p.h2[1] = __floats2half2_rn(v.z, v.w);
    ((uint2*)out)[i] = p.u;                          // 8B coalesced store
}

// ---- main: trilinear gather from fp16 volume -----------------------------
__global__ __launch_bounds__(256)
void ImageWarped_trilinear_h_kernel(const __half* __restrict__ image,
                                    const float* __restrict__ grid,
                                    float* __restrict__ out)
{
    const int i = blockIdx.x * 256 + threadIdx.x;
    if (i >= TOTAL) return;

    const float gx = grid[3 * i + 0];
    const float gy = grid[3 * i + 1];
    const float gz = grid[3 * i + 2];

    const int b = i >> LOG2N;
    const __half* __restrict__ img = image + (size_t)b * VOL;

    // idx = clip(grid * 128, 0.001, 126.999)
    const float xf = fminf(fmaxf(gx * 128.0f, 0.001f), 126.999f);
    const float yf = fminf(fmaxf(gy * 128.0f, 0.001f), 126.999f);
    const float zf = fminf(fmaxf(gz * 128.0f, 0.001f), 126.999f);

    const float x1f = floorf(xf), x2f = ceilf(xf);
    const float y1f = floorf(yf), y2f = ceilf(yf);
    const float z1f = floorf(zf), z2f = ceilf(zf);

    // Weights exactly as the reference (if coord integral, both weights 0).
    const float wx  = xf - x1f, wx2 = x2f - xf;
    const float wy  = yf - y1f, wy2 = y2f - yf;
    const float wz  = zf - z1f, wz2 = z2f - zf;

    const int ix1 = (int)x1f, ix2 = (int)x2f;
    const int iy1 = (int)y1f, iy2 = (int)y2f;
    const int iz1 = (int)z1f, iz2 = (int)z2f;

    const int bx1 = ix1 << 14, bx2 = ix2 << 14;   // x stride 16384
    const int by1 = iy1 << 7,  by2 = iy2 << 7;    // y stride 128

    const float c111 = __half2float(img[bx1 + by1 + iz1]);
    const float c211 = __half2float(img[bx2 + by1 + iz1]);
    const float c121 = __half2float(img[bx1 + by2 + iz1]);
    const float c221 = __half2float(img[bx2 + by2 + iz1]);
    const float c112 = __half2float(img[bx1 + by1 + iz2]);
    const float c212 = __half2float(img[bx2 + by1 + iz2]);
    const float c122 = __half2float(img[bx1 + by2 + iz2]);
    const float c222 = __half2float(img[bx2 + by2 + iz2]);

    const float lerp_y1 = (c211 * wx + c111 * wx2) * wy2
                        + (c221 * wx + c121 * wx2) * wy;
    const float lerp_y2 = (c212 * wx + c112 * wx2) * wy2
                        + (c222 * wx + c122 * wx2) * wy;

    out[i] = lerp_y2 * wz + lerp_y1 * wz2;
}

// ---- fallback (R1 kernel, fp32 gathers) if ws too small ------------------
__global__ __launch_bounds__(256)
void ImageWarped_trilinear_f_kernel(const float* __restrict__ image,
                                    const float* __restrict__ grid,
                                    float* __restrict__ out)
{
    const int i = blockIdx.x * 256 + threadIdx.x;
    if (i >= TOTAL) return;

    const float gx = grid[3 * i + 0];
    const float gy = grid[3 * i + 1];
    const float gz = grid[3 * i + 2];

    const int b = i >> LOG2N;
    const float* __restrict__ img = image + (size_t)b * VOL;

    const float xf = fminf(fmaxf(gx * 128.0f, 0.001f), 126.999f);
    const float yf = fminf(fmaxf(gy * 128.0f, 0.001f), 126.999f);
    const float zf = fminf(fmaxf(gz * 128.0f, 0.001f), 126.999f);

    const float x1f = floorf(xf), x2f = ceilf(xf);
    const float y1f = floorf(yf), y2f = ceilf(yf);
    const float z1f = floorf(zf), z2f = ceilf(zf);

    const float wx  = xf - x1f, wx2 = x2f - xf;
    const float wy  = yf - y1f, wy2 = y2f - yf;
    const float wz  = zf - z1f, wz2 = z2f - zf;

    const int ix1 = (int)x1f, ix2 = (int)x2f;
    const int iy1 = (int)y1f, iy2 = (int)y2f;
    const int iz1 = (int)z1f, iz2 = (int)z2f;

    const int bx1 = ix1 << 14, bx2 = ix2 << 14;
    const int by1 = iy1 << 7,  by2 = iy2 << 7;

    const float c111 = img[bx1 + by1 + iz1];
    const float c211 = img[bx2 + by1 + iz1];
    const float c121 = img[bx1 + by2 + iz1];
    const float c221 = img[bx2 + by2 + iz1];
    const float c112 = img[bx1 + by1 + iz2];
    const float c212 = img[bx2 + by1 + iz2];
    const float c122 = img[bx1 + by2 + iz2];
    const float c222 = img[bx2 + by2 + iz2];

    const float lerp_y1 = (c211 * wx + c111 * wx2) * wy2
                        + (c221 * wx + c121 * wx2) * wy;
    const float lerp_y2 = (c212 * wx + c112 * wx2) * wy2
                        + (c222 * wx + c122 * wx2) * wy;

    out[i] = lerp_y2 * wz + lerp_y1 * wz2;
}

extern "C" void kernel_launch(void* const* d_in, const int* in_sizes, int n_in,
                              void* d_out, int out_size, void* d_ws, size_t ws_size,
                              hipStream_t stream)
{
    const float* image = (const float*)d_in[0];  // [2,128,128,128,1] fp32
    const float* grid  = (const float*)d_in[1];  // [2,2097152,3]     fp32
    float* out = (float*)d_out;                  // [2,2097152,1]     fp32

    const int blocks = (TOTAL + 255) / 256;      // 16384

    if (ws_size >= (size_t)NVOX * sizeof(__half)) {
        __half* img16 = (__half*)d_ws;
        // convert 4 voxels/thread: NVOX/4 threads
        ImageWarped_cvt_fp16_kernel<<<NVOX / 4 / 256, 256, 0, stream>>>(image, img16);
        ImageWarped_trilinear_h_kernel<<<blocks, 256, 0, stream>>>(img16, grid, out);
    } else {
        ImageWarped_trilinear_f_kernel<<<blocks, 256, 0, stream>>>(image, grid, out);
    }
}

// Round 3
// 174.219 us; speedup vs baseline: 1.4949x; 1.2378x over previous
//
#include <hip/hip_runtime.h>
#include <hip/hip_fp16.h>

// Volume: [B=2, X=128, Y=128, Z=128, C=1] fp32, grid: [B=2, N=2^21, 3] in [0,1].
// Output: [B, N, 1] fp32 trilinear samples.
// image flat index = b*2^21 + x*2^14 + y*2^7 + z  (z fastest).
//
// R2: fp16 volume in d_ws (4.19 MiB/batch) -> FETCH 594->127 MB, 180->132 us.
// R3: (a) z-pair gathers: one 8B dwordx2 window of 4 halfs replaces two
//         ushort gathers -> 4 divergent loads/sample instead of 8
//         (512 -> 256 line-requests/wave on the TA pipe).
//     (b) XCD batch-parity swizzle: batch = blockIdx&1; with round-robin
//         blockIdx%8 -> XCD mapping each XCD caches only ONE batch's
//         4.19 MiB volume in its 4 MiB L2 (vs 8.4 MiB both batches).

#define TOTAL   (2 * 2097152)   // B * N samples
#define LOG2N   21              // N = 2^21 per batch; VOL = 2^21 voxels too
#define VOL     (128 * 128 * 128)
#define NVOX    (2 * VOL)

// ---- pre-pass: fp32 volume -> fp16 volume in workspace -------------------
__global__ __launch_bounds__(256)
void ImageWarped_cvt_fp16_kernel(const float* __restrict__ in,
                                 __half* __restrict__ out)
{
    const int i = blockIdx.x * 256 + threadIdx.x;   // NVOX/4 threads
    const float4 v = ((const float4*)in)[i];
    union { __half2 h2[2]; uint2 u; } p;
    p.h2[0] = __floats2half2_rn(v.x, v.y);
    p.h2[1] = __floats2half2_rn(v.z, v.w);
    ((uint2*)out)[i] = p.u;
}

// ---- main: trilinear gather, z-pairs via 8B windows ----------------------
__global__ __launch_bounds__(256)
void ImageWarped_trilinear_h2_kernel(const __half* __restrict__ image,
                                     const float* __restrict__ grid,
                                     float* __restrict__ out)
{
    // Batch-parity swizzle: even blocks sample batch 0, odd blocks batch 1.
    const int batch = blockIdx.x & 1;
    const int s     = (blockIdx.x >> 1) * 256 + threadIdx.x;  // within batch
    const int i     = (batch << LOG2N) | s;                   // global sample

    const float gx = grid[3 * i + 0];
    const float gy = grid[3 * i + 1];
    const float gz = grid[3 * i + 2];

    const __half* __restrict__ img = image + ((size_t)batch << LOG2N);

    // idx = clip(grid * 128, 0.001, 126.999)
    const float xf = fminf(fmaxf(gx * 128.0f, 0.001f), 126.999f);
    const float yf = fminf(fmaxf(gy * 128.0f, 0.001f), 126.999f);
    const float zf = fminf(fmaxf(gz * 128.0f, 0.001f), 126.999f);

    const float x1f = floorf(xf), x2f = ceilf(xf);
    const float y1f = floorf(yf), y2f = ceilf(yf);
    const float z1f = floorf(zf), z2f = ceilf(zf);

    // Literal two-weight form everywhere: if a coord is integral both its
    // weights are 0 (reference semantics), NOT w/1-w.
    const float wx  = xf - x1f, wx2 = x2f - xf;
    const float wy  = yf - y1f, wy2 = y2f - yf;
    const float wz  = zf - z1f, wz2 = z2f - zf;

    const int ix1 = (int)x1f, ix2 = (int)x2f;
    const int iy1 = (int)y1f, iy2 = (int)y2f;
    const int iz1 = (int)z1f;

    const int bx1 = ix1 << 14, bx2 = ix2 << 14;   // x stride 16384
    const int by1 = iy1 << 7,  by2 = iy2 << 7;    // y stride 128

    // 4-half window [ze, ze+3] always contains (z1, z1+1), stays in-bounds
    // (ze <= 124 -> ze+3 <= 127), and is 4B-aligned (ze even).
    const int ze = min(iz1 & ~1, 124);
    const int sh = (iz1 - ze) << 4;               // 0, 16, or 32 bits

    const float  ww  = wz2, wwz = wz;             // capture for lambda
    auto zfetch = [&](int off) -> float {
        const uint2 u = *(const uint2*)(img + off + ze);   // 8B, 4B-aligned
        unsigned long long w = ((unsigned long long)u.y << 32) | u.x;
        w >>= sh;
        union { unsigned int u32; __half2 h; } c;
        c.u32 = (unsigned int)w;                  // (c_z1, c_z2)
        const float2 f = __half22float2(c.h);
        return f.x * ww + f.y * wwz;              // z-lerp, literal form
    };

    const float q11 = zfetch(bx1 + by1);
    const float q21 = zfetch(bx2 + by1);
    const float q12 = zfetch(bx1 + by2);
    const float q22 = zfetch(bx2 + by2);

    // multilinear expansion == reference up to FP reassociation
    out[i] = (q21 * wx + q11 * wx2) * wy2
           + (q22 * wx + q12 * wx2) * wy;
}

// ---- fallback (R1 kernel, fp32 gathers) if ws too small ------------------
__global__ __launch_bounds__(256)
void ImageWarped_trilinear_f_kernel(const float* __restrict__ image,
                                    const float* __restrict__ grid,
                                    float* __restrict__ out)
{
    const int i = blockIdx.x * 256 + threadIdx.x;
    if (i >= TOTAL) return;

    const float gx = grid[3 * i + 0];
    const float gy = grid[3 * i + 1];
    const float gz = grid[3 * i + 2];

    const int b = i >> LOG2N;
    const float* __restrict__ img = image + (size_t)b * VOL;

    const float xf = fminf(fmaxf(gx * 128.0f, 0.001f), 126.999f);
    const float yf = fminf(fmaxf(gy * 128.0f, 0.001f), 126.999f);
    const float zf = fminf(fmaxf(gz * 128.0f, 0.001f), 126.999f);

    const float x1f = floorf(xf), x2f = ceilf(xf);
    const float y1f = floorf(yf), y2f = ceilf(yf);
    const float z1f = floorf(zf), z2f = ceilf(zf);

    const float wx  = xf - x1f, wx2 = x2f - xf;
    const float wy  = yf - y1f, wy2 = y2f - yf;
    const float wz  = zf - z1f, wz2 = z2f - zf;

    const int ix1 = (int)x1f, ix2 = (int)x2f;
    const int iy1 = (int)y1f, iy2 = (int)y2f;
    const int iz1 = (int)z1f, iz2 = (int)z2f;

    const int bx1 = ix1 << 14, bx2 = ix2 << 14;
    const int by1 = iy1 << 7,  by2 = iy2 << 7;

    const float c111 = img[bx1 + by1 + iz1];
    const float c211 = img[bx2 + by1 + iz1];
    const float c121 = img[bx1 + by2 + iz1];
    const float c221 = img[bx2 + by2 + iz1];
    const float c112 = img[bx1 + by1 + iz2];
    const float c212 = img[bx2 + by1 + iz2];
    const float c122 = img[bx1 + by2 + iz2];
    const float c222 = img[bx2 + by2 + iz2];

    const float lerp_y1 = (c211 * wx + c111 * wx2) * wy2
                        + (c221 * wx + c121 * wx2) * wy;
    const float lerp_y2 = (c212 * wx + c112 * wx2) * wy2
                        + (c222 * wx + c122 * wx2) * wy;

    out[i] = lerp_y2 * wz + lerp_y1 * wz2;
}

extern "C" void kernel_launch(void* const* d_in, const int* in_sizes, int n_in,
                              void* d_out, int out_size, void* d_ws, size_t ws_size,
                              hipStream_t stream)
{
    const float* image = (const float*)d_in[0];  // [2,128,128,128,1] fp32
    const float* grid  = (const float*)d_in[1];  // [2,2097152,3]     fp32
    float* out = (float*)d_out;                  // [2,2097152,1]     fp32

    const int blocks = (TOTAL + 255) / 256;      // 16384

    if (ws_size >= (size_t)NVOX * sizeof(__half)) {
        __half* img16 = (__half*)d_ws;
        ImageWarped_cvt_fp16_kernel<<<NVOX / 4 / 256, 256, 0, stream>>>(image, img16);
        ImageWarped_trilinear_h2_kernel<<<blocks, 256, 0, stream>>>(img16, grid, out);
    } else {
        ImageWarped_trilinear_f_kernel<<<blocks, 256, 0, stream>>>(image, grid, out);
    }
}